// Round 9
// baseline (901.266 us; speedup 1.0000x reference)
//
#include <hip/hip_runtime.h>
#include <hip/hip_cooperative_groups.h>
#include <math.h>

namespace cg = cooperative_groups;

#define NN 1024
#define WW 128
#define DD 1024
#define FF (NN * WW + NN)      // 132096
#define NROW (NN * WW)         // 131072
#define NCHUNK 516             // 256-float chunks per mask row
#define NWORD (NCHUNK * 4)     // 2064 u64 bitmap words per row
#define CWAVES 4096            // coop: 1024 blocks * 4 waves
#define GWAVES 8192            // fallback kernels: 2048 blocks * 4 waves

// ws layout: [feat: FF floats][bitmap: NN*NWORD u64][f1: NROW floats]
#define WS_BM_OFF  528384
#define WS_F1_OFF  (WS_BM_OFF + (size_t)NN * NWORD * 8)   // 17436672
#define WS_NEEDED  (WS_F1_OFF + (size_t)NROW * 4)         // 17960960

typedef float f32x4 __attribute__((ext_vector_type(4)));

__device__ __forceinline__ f32x4 nt4(const float* p) {
    return __builtin_nontemporal_load(reinterpret_cast<const f32x4*>(p));
}
__device__ __forceinline__ float wred(float s) {
    #pragma unroll
    for (int m = 32; m > 0; m >>= 1) s += __shfl_xor(s, m, 64);
    return s;
}
__device__ __forceinline__ float hred(float s) {   // reduce within each 32-lane half
    #pragma unroll
    for (int m = 16; m > 0; m >>= 1) s += __shfl_xor(s, m, 64);
    return s;
}

// ================= Cooperative mega-kernel: R7 phases, grid.sync boundaries =================
__global__ __launch_bounds__(256, 4) void coopK(
    const float* __restrict__ x, const float* __restrict__ hidden,
    const float* __restrict__ W1, const float* __restrict__ b1,
    const float* __restrict__ W2, const float* __restrict__ b2,
    const float* __restrict__ Wi, const float* __restrict__ bi,
    const float* __restrict__ mask, const float* __restrict__ pred,
    float* __restrict__ feat, unsigned long long* __restrict__ bm,
    float* __restrict__ f1, float* __restrict__ out)
{
    cg::grid_group grid = cg::this_grid();
    const int tid = threadIdx.x, lane = tid & 63, w = tid >> 6;
    const int gw = blockIdx.x * 4 + w;            // 0..4095
    __shared__ float partial[4];

    // ---- phase 1: f1 = relu(W1 @ x + b1), coherent front (32 MB/iter band) ----
    {
        const f32x4 xv0 = *reinterpret_cast<const f32x4*>(x +   0 + lane * 4);
        const f32x4 xv1 = *reinterpret_cast<const f32x4*>(x + 256 + lane * 4);
        const f32x4 xv2 = *reinterpret_cast<const f32x4*>(x + 512 + lane * 4);
        const f32x4 xv3 = *reinterpret_cast<const f32x4*>(x + 768 + lane * 4);
        #pragma unroll
        for (int i = 0; i < 16; ++i) {
            const int r = (i * CWAVES + gw) * 2;  // rows r, r+1
            const float* rp = W1 + (size_t)r * DD + lane * 4;
            f32x4 a0 = nt4(rp) * xv0;
            f32x4 a1 = nt4(rp + DD) * xv0;
            a0 += nt4(rp + 256) * xv1;
            a1 += nt4(rp + DD + 256) * xv1;
            a0 += nt4(rp + 512) * xv2;
            a1 += nt4(rp + DD + 512) * xv2;
            a0 += nt4(rp + 768) * xv3;
            a1 += nt4(rp + DD + 768) * xv3;
            float s0 = wred((a0[0] + a0[1]) + (a0[2] + a0[3]));
            float s1 = wred((a1[0] + a1[1]) + (a1[2] + a1[3]));
            if (lane == 0) {
                const float v0 = s0 + b1[r];
                const float v1 = s1 + b1[r + 1];
                f1[r]     = v0 > 0.f ? v0 : 0.f;
                f1[r + 1] = v1 > 0.f ? v1 : 0.f;
            }
        }
    }
    __threadfence();
    grid.sync();

    // ---- phase 2a: f2 = relu(W2 @ f1 + b2) -> feat, coherent front over W2 ----
    {
        const int gtid = blockIdx.x * 256 + tid;
        if (gtid < NN) feat[NROW + gtid] = hidden[gtid];  // hidden tail
        #pragma unroll
        for (int i = 0; i < 16; ++i) {
            const int p  = i * CWAVES + gw;       // row-pair 0..65535
            const int rr = p * 2;
            const int n  = p >> 6;
            const f32x4 wv = nt4(W2 + (size_t)p * 256 + lane * 4);
            const f32x4 fv = *reinterpret_cast<const f32x4*>(f1 + (n << 7) + ((lane & 31) << 2));
            const f32x4 m = wv * fv;
            const float s = hred((m[0] + m[1]) + (m[2] + m[3]));
            if (lane == 0) {
                const float v = s + b2[rr];
                feat[rr] = v > 0.f ? v : 0.f;
            } else if (lane == 32) {
                const float v = s + b2[rr + 1];
                feat[rr + 1] = v > 0.f ? v : 0.f;
            }
        }
    }

    // ---- phase 2b: mask -> bitmap, coherent grid-stride front ----
    #pragma unroll 2
    for (int c = gw; c < NN * NCHUNK; c += CWAVES) {
        const f32x4 m = nt4(mask + (size_t)c * 256 + lane * 4);
        const unsigned long long q0 = __ballot(m[0] != 0.f);
        const unsigned long long q1 = __ballot(m[1] != 0.f);
        const unsigned long long q2 = __ballot(m[2] != 0.f);
        const unsigned long long q3 = __ballot(m[3] != 0.f);
        if (lane < 4) {
            const unsigned long long v = lane == 0 ? q0 : lane == 1 ? q1 : lane == 2 ? q2 : q3;
            bm[(size_t)c * 4 + lane] = v;
        }
    }
    __threadfence();
    grid.sync();

    // ---- phase 3: bitmap-driven sparse dot + tanh + h (1 row per block) ----
    {
        const int n = blockIdx.x;
        const unsigned long long* brow = bm + (size_t)n * NWORD;
        const float* wrow = Wi + (size_t)n * FF;
        float acc = 0.f;
        for (int wd = tid; wd < NWORD; wd += 256) {
            unsigned long long q = brow[wd];
            const int basef = (wd >> 2) * 256 + (wd & 3);
            while (q) {
                const int l = __builtin_ctzll(q);
                const int f = basef + l * 4;
                acc += wrow[f] * feat[f];   // mask value is exactly 1.0
                q &= q - 1;
            }
        }
        acc = wred(acc);
        if (lane == 0) partial[w] = acc;
        __syncthreads();
        if (tid == 0) {
            const float s = (partial[0] + partial[1]) + (partial[2] + partial[3]);
            out[1 + n] = hidden[n] + tanhf(s + bi[n]);
        }
    }
    __threadfence();
    grid.sync();

    // ---- phase 4: y = sum(pred * h), block 0 ----
    if (blockIdx.x == 0) {
        float acc = 0.f;
        for (int i = tid; i < NN; i += 256) acc += pred[i] * out[1 + i];
        acc = wred(acc);
        __syncthreads();   // reuse partial[] safely after phase 3
        if (lane == 0) partial[w] = acc;
        __syncthreads();
        if (tid == 0) out[0] = (partial[0] + partial[1]) + (partial[2] + partial[3]);
    }
}

// ================= R7 fallback kernels (proven 211.7 µs path) =================
__global__ __launch_bounds__(256) void w1dot(
    const float* __restrict__ x, const float* __restrict__ W1,
    const float* __restrict__ b1, float* __restrict__ f1)
{
    const int tid = threadIdx.x, lane = tid & 63;
    const int gw = blockIdx.x * 4 + (tid >> 6);   // 0..8191
    const f32x4 xv0 = *reinterpret_cast<const f32x4*>(x +   0 + lane * 4);
    const f32x4 xv1 = *reinterpret_cast<const f32x4*>(x + 256 + lane * 4);
    const f32x4 xv2 = *reinterpret_cast<const f32x4*>(x + 512 + lane * 4);
    const f32x4 xv3 = *reinterpret_cast<const f32x4*>(x + 768 + lane * 4);
    #pragma unroll
    for (int i = 0; i < 8; ++i) {
        const int r = (i * GWAVES + gw) * 2;
        const float* rp = W1 + (size_t)r * DD + lane * 4;
        f32x4 a0 = nt4(rp) * xv0;
        f32x4 a1 = nt4(rp + DD) * xv0;
        a0 += nt4(rp + 256) * xv1;
        a1 += nt4(rp + DD + 256) * xv1;
        a0 += nt4(rp + 512) * xv2;
        a1 += nt4(rp + DD + 512) * xv2;
        a0 += nt4(rp + 768) * xv3;
        a1 += nt4(rp + DD + 768) * xv3;
        float s0 = wred((a0[0] + a0[1]) + (a0[2] + a0[3]));
        float s1 = wred((a1[0] + a1[1]) + (a1[2] + a1[3]));
        if (lane == 0) {
            const float v0 = s0 + b1[r];
            const float v1 = s1 + b1[r + 1];
            f1[r]     = v0 > 0.f ? v0 : 0.f;
            f1[r + 1] = v1 > 0.f ? v1 : 0.f;
        }
    }
}

__global__ __launch_bounds__(256) void w2dot(
    const float* __restrict__ W2, const float* __restrict__ b2,
    const float* __restrict__ f1, const float* __restrict__ hidden,
    float* __restrict__ feat)
{
    const int tid = threadIdx.x, lane = tid & 63;
    const int gw = blockIdx.x * 4 + (tid >> 6);
    const int gtid = blockIdx.x * 256 + tid;
    if (gtid < NN) feat[NROW + gtid] = hidden[gtid];
    #pragma unroll
    for (int i = 0; i < 8; ++i) {
        const int p  = i * GWAVES + gw;
        const int rr = p * 2;
        const int n  = p >> 6;
        const f32x4 wv = nt4(W2 + (size_t)p * 256 + lane * 4);
        const f32x4 fv = *reinterpret_cast<const f32x4*>(f1 + (n << 7) + ((lane & 31) << 2));
        const f32x4 m = wv * fv;
        const float s = hred((m[0] + m[1]) + (m[2] + m[3]));
        if (lane == 0) {
            const float v = s + b2[rr];
            feat[rr] = v > 0.f ? v : 0.f;
        } else if (lane == 32) {
            const float v = s + b2[rr + 1];
            feat[rr + 1] = v > 0.f ? v : 0.f;
        }
    }
}

__global__ __launch_bounds__(256) void maskscan(
    const float* __restrict__ mask, unsigned long long* __restrict__ bm)
{
    const int tid = threadIdx.x, lane = tid & 63, w = tid >> 6;
    const int wave_id = blockIdx.x * 4 + w;
    const int nwaves  = gridDim.x * 4;
    #pragma unroll 2
    for (int c = wave_id; c < NN * NCHUNK; c += nwaves) {
        const f32x4 m = nt4(mask + (size_t)c * 256 + lane * 4);
        const unsigned long long q0 = __ballot(m[0] != 0.f);
        const unsigned long long q1 = __ballot(m[1] != 0.f);
        const unsigned long long q2 = __ballot(m[2] != 0.f);
        const unsigned long long q3 = __ballot(m[3] != 0.f);
        if (lane < 4) {
            const unsigned long long v = lane == 0 ? q0 : lane == 1 ? q1 : lane == 2 ? q2 : q3;
            bm[(size_t)c * 4 + lane] = v;
        }
    }
}

__global__ __launch_bounds__(256) void dotk(
    const unsigned long long* __restrict__ bm, const float* __restrict__ Wi,
    const float* __restrict__ feat, const float* __restrict__ bi,
    const float* __restrict__ hidden, float* __restrict__ out)
{
    const int n = blockIdx.x, tid = threadIdx.x;
    const unsigned long long* brow = bm + (size_t)n * NWORD;
    const float* wrow = Wi + (size_t)n * FF;
    float acc = 0.f;
    for (int wd = tid; wd < NWORD; wd += 256) {
        unsigned long long q = brow[wd];
        const int basef = (wd >> 2) * 256 + (wd & 3);
        while (q) {
            const int l = __builtin_ctzll(q);
            const int f = basef + l * 4;
            acc += wrow[f] * feat[f];
            q &= q - 1;
        }
    }
    acc = wred(acc);
    __shared__ float partial[4];
    if ((tid & 63) == 0) partial[tid >> 6] = acc;
    __syncthreads();
    if (tid == 0) {
        const float s = (partial[0] + partial[1]) + (partial[2] + partial[3]);
        out[1 + n] = hidden[n] + tanhf(s + bi[n]);
    }
}

__global__ __launch_bounds__(256) void predk(
    const float* __restrict__ pred, const float* __restrict__ h,
    float* __restrict__ out)
{
    const int tid = threadIdx.x;
    float acc = 0.f;
    for (int i = tid; i < NN; i += 256) acc += pred[i] * h[i];
    acc = wred(acc);
    __shared__ float partial[4];
    if ((tid & 63) == 0) partial[tid >> 6] = acc;
    __syncthreads();
    if (tid == 0) out[0] = (partial[0] + partial[1]) + (partial[2] + partial[3]);
}

// ---------------- minimal fallback if ws too small ----------------
__global__ __launch_bounds__(256) void feat_kernel(
    const float* __restrict__ x, const float* __restrict__ hidden,
    const float* __restrict__ W1, const float* __restrict__ b1,
    const float* __restrict__ W2, const float* __restrict__ b2,
    float* __restrict__ feat)
{
    const int n = blockIdx.x, tid = threadIdx.x, lane = tid & 63, wave = tid >> 6;
    __shared__ float x_s[DD];
    __shared__ float f1_s[WW];
    *reinterpret_cast<float4*>(x_s + tid * 4) = *reinterpret_cast<const float4*>(x + tid * 4);
    if (tid == 0) feat[NROW + n] = hidden[n];
    __syncthreads();
    const float* W1n = W1 + (size_t)n * WW * DD;
    for (int r = wave * 32; r < wave * 32 + 32; ++r) {
        const float* row = W1n + (size_t)r * DD;
        float4 acc = {0.f, 0.f, 0.f, 0.f};
        #pragma unroll
        for (int it = 0; it < 4; ++it) {
            const float4 a  = *reinterpret_cast<const float4*>(row + it * 256 + lane * 4);
            const float4 xv = *reinterpret_cast<const float4*>(x_s + it * 256 + lane * 4);
            acc.x += a.x * xv.x; acc.y += a.y * xv.y;
            acc.z += a.z * xv.z; acc.w += a.w * xv.w;
        }
        float s = wred((acc.x + acc.y) + (acc.z + acc.w));
        if (lane == 0) {
            float v = s + b1[n * WW + r];
            f1_s[r] = v > 0.f ? v : 0.f;
        }
    }
    __syncthreads();
    const float* W2n = W2 + (size_t)n * WW * WW;
    for (int r = wave * 32; r < wave * 32 + 32; ++r) {
        const float2 a = *reinterpret_cast<const float2*>(W2n + (size_t)r * WW + lane * 2);
        const float2 f = *reinterpret_cast<const float2*>(f1_s + lane * 2);
        float s = wred(a.x * f.x + a.y * f.y);
        if (lane == 0) {
            float v = s + b2[n * WW + r];
            feat[n * WW + r] = v > 0.f ? v : 0.f;
        }
    }
}

__global__ __launch_bounds__(256) void sparse_kernel(
    const float* __restrict__ Wi, const float* __restrict__ mask,
    const float* __restrict__ bi, const float* __restrict__ hidden,
    const float* __restrict__ feat, float* __restrict__ out)
{
    const int n = blockIdx.x, tid = threadIdx.x;
    const float* mrow = mask + (size_t)n * FF;
    const float* wrow = Wi   + (size_t)n * FF;
    float acc = 0.f;
    for (int it = 0; it < FF / 1024; ++it) {
        const int f = it * 1024 + tid * 4;
        const float4 m = *reinterpret_cast<const float4*>(mrow + f);
        if (m.x != 0.f) acc += wrow[f + 0] * m.x * feat[f + 0];
        if (m.y != 0.f) acc += wrow[f + 1] * m.y * feat[f + 1];
        if (m.z != 0.f) acc += wrow[f + 2] * m.z * feat[f + 2];
        if (m.w != 0.f) acc += wrow[f + 3] * m.w * feat[f + 3];
    }
    acc = wred(acc);
    __shared__ float partial[4];
    if ((tid & 63) == 0) partial[tid >> 6] = acc;
    __syncthreads();
    if (tid == 0) {
        const float s = (partial[0] + partial[1]) + (partial[2] + partial[3]);
        out[1 + n] = hidden[n] + tanhf(s + bi[n]);
    }
}

extern "C" void kernel_launch(void* const* d_in, const int* in_sizes, int n_in,
                              void* d_out, int out_size, void* d_ws, size_t ws_size,
                              hipStream_t stream) {
    const float* x      = (const float*)d_in[0];
    const float* hidden = (const float*)d_in[1];
    const float* W1     = (const float*)d_in[2];
    const float* b1     = (const float*)d_in[3];
    const float* W2     = (const float*)d_in[4];
    const float* b2     = (const float*)d_in[5];
    const float* Wi     = (const float*)d_in[6];
    const float* bi     = (const float*)d_in[7];
    const float* mask   = (const float*)d_in[8];
    const float* pred   = (const float*)d_in[9];

    float* out  = (float*)d_out;
    float* feat = (float*)d_ws;
    unsigned long long* bm = (unsigned long long*)((char*)d_ws + WS_BM_OFF);
    float* f1 = (float*)((char*)d_ws + WS_F1_OFF);

    if (ws_size >= WS_NEEDED) {
        void* args[] = {
            (void*)&x, (void*)&hidden, (void*)&W1, (void*)&b1,
            (void*)&W2, (void*)&b2, (void*)&Wi, (void*)&bi,
            (void*)&mask, (void*)&pred,
            (void*)&feat, (void*)&bm, (void*)&f1, (void*)&out
        };
        hipError_t rc = hipLaunchCooperativeKernel(
            (const void*)coopK, dim3(1024), dim3(256), args, 0, stream);
        if (rc != hipSuccess) {
            // R7-proven serial path
            w1dot<<<2048, 256, 0, stream>>>(x, W1, b1, f1);
            w2dot<<<2048, 256, 0, stream>>>(W2, b2, f1, hidden, feat);
            maskscan<<<2048, 256, 0, stream>>>(mask, bm);
            dotk<<<NN, 256, 0, stream>>>(bm, Wi, feat, bi, hidden, out);
            predk<<<1, 256, 0, stream>>>(pred, out + 1, out);
        }
    } else {
        feat_kernel<<<NN, 256, 0, stream>>>(x, hidden, W1, b1, W2, b2, feat);
        sparse_kernel<<<NN, 256, 0, stream>>>(Wi, mask, bi, hidden, feat, out);
        predk<<<1, 256, 0, stream>>>(pred, out + 1, out);
    }
}

// Round 10
// 210.033 us; speedup vs baseline: 4.2911x; 4.2911x over previous
//
#include <hip/hip_runtime.h>
#include <math.h>

#define NN 1024
#define WW 128
#define DD 1024
#define FF (NN * WW + NN)      // 132096
#define NROW (NN * WW)         // 131072
#define NCHUNK 516             // 256-float chunks per mask row
#define NWORD (NCHUNK * 4)     // 2064 u64 bitmap words per row
#define GWAVES 8192            // 2048 blocks * 4 waves

// ws layout: [feat: FF floats][bitmap: NN*NWORD u64][f1: NROW floats]
#define WS_BM_OFF  528384
#define WS_F1_OFF  (WS_BM_OFF + (size_t)NN * NWORD * 8)   // 17436672
#define WS_NEEDED  (WS_F1_OFF + (size_t)NROW * 4)         // 17960960

typedef float f32x4 __attribute__((ext_vector_type(4)));

__device__ __forceinline__ f32x4 nt4(const float* p) {
    return __builtin_nontemporal_load(reinterpret_cast<const f32x4*>(p));
}
__device__ __forceinline__ float wred(float s) {
    #pragma unroll
    for (int m = 32; m > 0; m >>= 1) s += __shfl_xor(s, m, 64);
    return s;
}
__device__ __forceinline__ float hred(float s) {   // reduce within each 32-lane half
    #pragma unroll
    for (int m = 16; m > 0; m >>= 1) s += __shfl_xor(s, m, 64);
    return s;
}

// ---------------- K1: f1 = relu(W1 @ x + b1), single coherent front (R7-proven) ----------------
__global__ __launch_bounds__(256) void w1dot(
    const float* __restrict__ x, const float* __restrict__ W1,
    const float* __restrict__ b1, float* __restrict__ f1)
{
    const int tid = threadIdx.x, lane = tid & 63;
    const int gw = blockIdx.x * 4 + (tid >> 6);   // 0..8191
    const f32x4 xv0 = *reinterpret_cast<const f32x4*>(x +   0 + lane * 4);
    const f32x4 xv1 = *reinterpret_cast<const f32x4*>(x + 256 + lane * 4);
    const f32x4 xv2 = *reinterpret_cast<const f32x4*>(x + 512 + lane * 4);
    const f32x4 xv3 = *reinterpret_cast<const f32x4*>(x + 768 + lane * 4);
    #pragma unroll
    for (int i = 0; i < 8; ++i) {
        const int r = (i * GWAVES + gw) * 2;      // rows r, r+1; grid covers 64MB/iter
        const float* rp = W1 + (size_t)r * DD + lane * 4;
        f32x4 a0 = nt4(rp) * xv0;
        f32x4 a1 = nt4(rp + DD) * xv0;
        a0 += nt4(rp + 256) * xv1;
        a1 += nt4(rp + DD + 256) * xv1;
        a0 += nt4(rp + 512) * xv2;
        a1 += nt4(rp + DD + 512) * xv2;
        a0 += nt4(rp + 768) * xv3;
        a1 += nt4(rp + DD + 768) * xv3;
        float s0 = wred((a0[0] + a0[1]) + (a0[2] + a0[3]));
        float s1 = wred((a1[0] + a1[1]) + (a1[2] + a1[3]));
        if (lane == 0) {
            const float v0 = s0 + b1[r];
            const float v1 = s1 + b1[r + 1];
            f1[r]     = v0 > 0.f ? v0 : 0.f;
            f1[r + 1] = v1 > 0.f ? v1 : 0.f;
        }
    }
}

// ---------------- K2: W2 front then mask front, sequential within one launch ----------------
// The two phases are mutually independent (no sync needed); each is a single
// coherent grid-wide sweep, entered by all blocks at nearly the same time.
__global__ __launch_bounds__(256) void w2mask(
    const float* __restrict__ W2, const float* __restrict__ b2,
    const float* __restrict__ f1, const float* __restrict__ hidden,
    float* __restrict__ feat,
    const float* __restrict__ mask, unsigned long long* __restrict__ bm)
{
    const int tid = threadIdx.x, lane = tid & 63, w = tid >> 6;
    const int gw = blockIdx.x * 4 + w;
    const int gtid = blockIdx.x * 256 + tid;
    if (gtid < NN) feat[NROW + gtid] = hidden[gtid];  // hidden tail

    // ---- phase A: f2 = relu(W2 @ f1 + b2) -> feat (R7 w2dot) ----
    #pragma unroll
    for (int i = 0; i < 8; ++i) {
        const int p  = i * GWAVES + gw;           // row-pair index, 0..65535
        const int rr = p * 2;                     // rows rr, rr+1 (same column n)
        const int n  = p >> 6;
        const f32x4 wv = nt4(W2 + (size_t)p * 256 + lane * 4);
        const f32x4 fv = *reinterpret_cast<const f32x4*>(f1 + (n << 7) + ((lane & 31) << 2));
        const f32x4 m = wv * fv;
        const float s = hred((m[0] + m[1]) + (m[2] + m[3]));
        if (lane == 0) {
            const float v = s + b2[rr];
            feat[rr] = v > 0.f ? v : 0.f;
        } else if (lane == 32) {
            const float v = s + b2[rr + 1];
            feat[rr + 1] = v > 0.f ? v : 0.f;
        }
    }

    // ---- phase B: mask -> bitmap, coherent grid-stride front (unroll 4) ----
    #pragma unroll 4
    for (int c = gw; c < NN * NCHUNK; c += GWAVES) {
        const f32x4 m = nt4(mask + (size_t)c * 256 + lane * 4);
        const unsigned long long q0 = __ballot(m[0] != 0.f);
        const unsigned long long q1 = __ballot(m[1] != 0.f);
        const unsigned long long q2 = __ballot(m[2] != 0.f);
        const unsigned long long q3 = __ballot(m[3] != 0.f);
        if (lane < 4) {
            const unsigned long long v = lane == 0 ? q0 : lane == 1 ? q1 : lane == 2 ? q2 : q3;
            bm[(size_t)c * 4 + lane] = v;
        }
    }
}

// ---------------- K3: bitmap-driven sparse dot + tanh + h ----------------
__global__ __launch_bounds__(256) void dotk(
    const unsigned long long* __restrict__ bm, const float* __restrict__ Wi,
    const float* __restrict__ feat, const float* __restrict__ bi,
    const float* __restrict__ hidden, float* __restrict__ out)
{
    const int n = blockIdx.x, tid = threadIdx.x;
    const unsigned long long* brow = bm + (size_t)n * NWORD;
    const float* wrow = Wi + (size_t)n * FF;
    float acc = 0.f;
    for (int wd = tid; wd < NWORD; wd += 256) {
        unsigned long long q = brow[wd];
        const int basef = (wd >> 2) * 256 + (wd & 3);
        while (q) {
            const int l = __builtin_ctzll(q);
            const int f = basef + l * 4;
            acc += wrow[f] * feat[f];   // mask value is exactly 1.0
            q &= q - 1;
        }
    }
    acc = wred(acc);
    __shared__ float partial[4];
    if ((tid & 63) == 0) partial[tid >> 6] = acc;
    __syncthreads();
    if (tid == 0) {
        const float s = (partial[0] + partial[1]) + (partial[2] + partial[3]);
        out[1 + n] = hidden[n] + tanhf(s + bi[n]);
    }
}

// ---------------- K4: y = sum(pred * h) ----------------
__global__ __launch_bounds__(256) void predk(
    const float* __restrict__ pred, const float* __restrict__ h,
    float* __restrict__ out)
{
    const int tid = threadIdx.x;
    float acc = 0.f;
    for (int i = tid; i < NN; i += 256) acc += pred[i] * h[i];
    acc = wred(acc);
    __shared__ float partial[4];
    if ((tid & 63) == 0) partial[tid >> 6] = acc;
    __syncthreads();
    if (tid == 0) out[0] = (partial[0] + partial[1]) + (partial[2] + partial[3]);
}

// ---------------- minimal fallback if ws too small ----------------
__global__ __launch_bounds__(256) void feat_kernel(
    const float* __restrict__ x, const float* __restrict__ hidden,
    const float* __restrict__ W1, const float* __restrict__ b1,
    const float* __restrict__ W2, const float* __restrict__ b2,
    float* __restrict__ feat)
{
    const int n = blockIdx.x, tid = threadIdx.x, lane = tid & 63, wave = tid >> 6;
    __shared__ float x_s[DD];
    __shared__ float f1_s[WW];
    *reinterpret_cast<float4*>(x_s + tid * 4) = *reinterpret_cast<const float4*>(x + tid * 4);
    if (tid == 0) feat[NROW + n] = hidden[n];
    __syncthreads();
    const float* W1n = W1 + (size_t)n * WW * DD;
    for (int r = wave * 32; r < wave * 32 + 32; ++r) {
        const float* row = W1n + (size_t)r * DD;
        float4 acc = {0.f, 0.f, 0.f, 0.f};
        #pragma unroll
        for (int it = 0; it < 4; ++it) {
            const float4 a  = *reinterpret_cast<const float4*>(row + it * 256 + lane * 4);
            const float4 xv = *reinterpret_cast<const float4*>(x_s + it * 256 + lane * 4);
            acc.x += a.x * xv.x; acc.y += a.y * xv.y;
            acc.z += a.z * xv.z; acc.w += a.w * xv.w;
        }
        float s = wred((acc.x + acc.y) + (acc.z + acc.w));
        if (lane == 0) {
            float v = s + b1[n * WW + r];
            f1_s[r] = v > 0.f ? v : 0.f;
        }
    }
    __syncthreads();
    const float* W2n = W2 + (size_t)n * WW * WW;
    for (int r = wave * 32; r < wave * 32 + 32; ++r) {
        const float2 a = *reinterpret_cast<const float2*>(W2n + (size_t)r * WW + lane * 2);
        const float2 f = *reinterpret_cast<const float2*>(f1_s + lane * 2);
        float s = wred(a.x * f.x + a.y * f.y);
        if (lane == 0) {
            float v = s + b2[n * WW + r];
            feat[n * WW + r] = v > 0.f ? v : 0.f;
        }
    }
}

__global__ __launch_bounds__(256) void sparse_kernel(
    const float* __restrict__ Wi, const float* __restrict__ mask,
    const float* __restrict__ bi, const float* __restrict__ hidden,
    const float* __restrict__ feat, float* __restrict__ out)
{
    const int n = blockIdx.x, tid = threadIdx.x;
    const float* mrow = mask + (size_t)n * FF;
    const float* wrow = Wi   + (size_t)n * FF;
    float acc = 0.f;
    for (int it = 0; it < FF / 1024; ++it) {
        const int f = it * 1024 + tid * 4;
        const float4 m = *reinterpret_cast<const float4*>(mrow + f);
        if (m.x != 0.f) acc += wrow[f + 0] * m.x * feat[f + 0];
        if (m.y != 0.f) acc += wrow[f + 1] * m.y * feat[f + 1];
        if (m.z != 0.f) acc += wrow[f + 2] * m.z * feat[f + 2];
        if (m.w != 0.f) acc += wrow[f + 3] * m.w * feat[f + 3];
    }
    acc = wred(acc);
    __shared__ float partial[4];
    if ((tid & 63) == 0) partial[tid >> 6] = acc;
    __syncthreads();
    if (tid == 0) {
        const float s = (partial[0] + partial[1]) + (partial[2] + partial[3]);
        out[1 + n] = hidden[n] + tanhf(s + bi[n]);
    }
}

extern "C" void kernel_launch(void* const* d_in, const int* in_sizes, int n_in,
                              void* d_out, int out_size, void* d_ws, size_t ws_size,
                              hipStream_t stream) {
    const float* x      = (const float*)d_in[0];
    const float* hidden = (const float*)d_in[1];
    const float* W1     = (const float*)d_in[2];
    const float* b1     = (const float*)d_in[3];
    const float* W2     = (const float*)d_in[4];
    const float* b2     = (const float*)d_in[5];
    const float* Wi     = (const float*)d_in[6];
    const float* bi     = (const float*)d_in[7];
    const float* mask   = (const float*)d_in[8];
    const float* pred   = (const float*)d_in[9];

    float* out  = (float*)d_out;
    float* feat = (float*)d_ws;
    unsigned long long* bm = (unsigned long long*)((char*)d_ws + WS_BM_OFF);
    float* f1 = (float*)((char*)d_ws + WS_F1_OFF);

    if (ws_size >= WS_NEEDED) {
        w1dot<<<2048, 256, 0, stream>>>(x, W1, b1, f1);
        w2mask<<<2048, 256, 0, stream>>>(W2, b2, f1, hidden, feat, mask, bm);
        dotk<<<NN, 256, 0, stream>>>(bm, Wi, feat, bi, hidden, out);
    } else {
        feat_kernel<<<NN, 256, 0, stream>>>(x, hidden, W1, b1, W2, b2, feat);
        sparse_kernel<<<NN, 256, 0, stream>>>(Wi, mask, bi, hidden, feat, out);
    }
    predk<<<1, 256, 0, stream>>>(pred, out + 1, out);
}

// Round 11
// 202.305 us; speedup vs baseline: 4.4550x; 1.0382x over previous
//
#include <hip/hip_runtime.h>
#include <math.h>

#define NN 1024
#define WW 128
#define DD 1024
#define FF (NN * WW + NN)      // 132096 = 516*256
#define NROW (NN * WW)         // 131072
#define NCHUNK 516             // 256-float chunks per mask row
#define GWAVES 8192            // 2048 blocks * 4 waves

// ws layout: [feat: FF floats][f1: NROW floats][partial: NN*NCHUNK floats]
#define WS_F1_OFF   528384
#define WS_PART_OFF (WS_F1_OFF + (size_t)NROW * 4)        // 1052672
#define WS_NEEDED   (WS_PART_OFF + (size_t)NN * NCHUNK * 4) // 3166208

typedef float f32x4 __attribute__((ext_vector_type(4)));

__device__ __forceinline__ f32x4 nt4(const float* p) {
    return __builtin_nontemporal_load(reinterpret_cast<const f32x4*>(p));
}
__device__ __forceinline__ float wred(float s) {
    #pragma unroll
    for (int m = 32; m > 0; m >>= 1) s += __shfl_xor(s, m, 64);
    return s;
}
__device__ __forceinline__ float hred(float s) {   // reduce within each 32-lane half
    #pragma unroll
    for (int m = 16; m > 0; m >>= 1) s += __shfl_xor(s, m, 64);
    return s;
}

// ---------------- K1: f1 = relu(W1 @ x + b1), single coherent front (R7-proven) ----------------
__global__ __launch_bounds__(256) void w1dot(
    const float* __restrict__ x, const float* __restrict__ W1,
    const float* __restrict__ b1, float* __restrict__ f1)
{
    const int tid = threadIdx.x, lane = tid & 63;
    const int gw = blockIdx.x * 4 + (tid >> 6);   // 0..8191
    const f32x4 xv0 = *reinterpret_cast<const f32x4*>(x +   0 + lane * 4);
    const f32x4 xv1 = *reinterpret_cast<const f32x4*>(x + 256 + lane * 4);
    const f32x4 xv2 = *reinterpret_cast<const f32x4*>(x + 512 + lane * 4);
    const f32x4 xv3 = *reinterpret_cast<const f32x4*>(x + 768 + lane * 4);
    #pragma unroll
    for (int i = 0; i < 8; ++i) {
        const int r = (i * GWAVES + gw) * 2;      // rows r, r+1; grid covers 64MB/iter
        const float* rp = W1 + (size_t)r * DD + lane * 4;
        f32x4 a0 = nt4(rp) * xv0;
        f32x4 a1 = nt4(rp + DD) * xv0;
        a0 += nt4(rp + 256) * xv1;
        a1 += nt4(rp + DD + 256) * xv1;
        a0 += nt4(rp + 512) * xv2;
        a1 += nt4(rp + DD + 512) * xv2;
        a0 += nt4(rp + 768) * xv3;
        a1 += nt4(rp + DD + 768) * xv3;
        float s0 = wred((a0[0] + a0[1]) + (a0[2] + a0[3]));
        float s1 = wred((a1[0] + a1[1]) + (a1[2] + a1[3]));
        if (lane == 0) {
            const float v0 = s0 + b1[r];
            const float v1 = s1 + b1[r + 1];
            f1[r]     = v0 > 0.f ? v0 : 0.f;
            f1[r + 1] = v1 > 0.f ? v1 : 0.f;
        }
    }
}

// ---------------- K2: f2 = relu(W2 @ f1 + b2) -> feat, single coherent front ----------------
__global__ __launch_bounds__(256) void w2dot(
    const float* __restrict__ W2, const float* __restrict__ b2,
    const float* __restrict__ f1, const float* __restrict__ hidden,
    float* __restrict__ feat)
{
    const int tid = threadIdx.x, lane = tid & 63;
    const int gw = blockIdx.x * 4 + (tid >> 6);
    const int gtid = blockIdx.x * 256 + tid;
    if (gtid < NN) feat[NROW + gtid] = hidden[gtid];  // hidden tail
    #pragma unroll
    for (int i = 0; i < 8; ++i) {
        const int p  = i * GWAVES + gw;           // row-pair index, 0..65535
        const int rr = p * 2;                     // rows rr, rr+1 (same column n)
        const int n  = p >> 6;
        const f32x4 wv = nt4(W2 + (size_t)p * 256 + lane * 4);
        const f32x4 fv = *reinterpret_cast<const f32x4*>(f1 + (n << 7) + ((lane & 31) << 2));
        const f32x4 m = wv * fv;
        const float s = hred((m[0] + m[1]) + (m[2] + m[3]));
        if (lane == 0) {
            const float v = s + b2[rr];
            feat[rr] = v > 0.f ? v : 0.f;
        } else if (lane == 32) {
            const float v = s + b2[rr + 1];
            feat[rr + 1] = v > 0.f ? v : 0.f;
        }
    }
}

// ---------------- K3: coherent mask sweep + inline sparse gather -> per-chunk partials ----------------
// chunk c = row n = c/NCHUNK, local offset (c%NCHUNK)*256. Global flat index == c*256 + ...
// since FF == NCHUNK*256. Each wave reduces its chunk's hits in fixed lane/element order
// (deterministic) and writes exactly one float partial[c].
__global__ __launch_bounds__(256) void scangather(
    const float* __restrict__ mask, const float* __restrict__ Wi,
    const float* __restrict__ feat, float* __restrict__ partial)
{
    const int tid = threadIdx.x, lane = tid & 63, w = tid >> 6;
    const int wave_id = blockIdx.x * 4 + w;
    #pragma unroll 2
    for (int c = wave_id; c < NN * NCHUNK; c += GWAVES) {
        const f32x4 m = nt4(mask + (size_t)c * 256 + lane * 4);
        float a = 0.f;
        if ((m[0] != 0.f) || (m[1] != 0.f) || (m[2] != 0.f) || (m[3] != 0.f)) {
            const int n  = c / NCHUNK;
            const int fl = (c - n * NCHUNK) * 256 + lane * 4;
            const float* wrow = Wi + (size_t)n * FF;
            if (m[0] != 0.f) a += wrow[fl]     * feat[fl];
            if (m[1] != 0.f) a += wrow[fl + 1] * feat[fl + 1];
            if (m[2] != 0.f) a += wrow[fl + 2] * feat[fl + 2];
            if (m[3] != 0.f) a += wrow[fl + 3] * feat[fl + 3];
        }
        const float s = wred(a);
        if (lane == 0) partial[c] = s;
    }
}

// ---------------- K4: per-row sum of partials + tanh + h ----------------
__global__ __launch_bounds__(256) void sumk(
    const float* __restrict__ partial, const float* __restrict__ bi,
    const float* __restrict__ hidden, float* __restrict__ out)
{
    const int n = blockIdx.x, tid = threadIdx.x;
    const float* prow = partial + (size_t)n * NCHUNK;
    float acc = 0.f;
    for (int j = tid; j < NCHUNK; j += 256) acc += prow[j];
    acc = wred(acc);
    __shared__ float p4[4];
    if ((tid & 63) == 0) p4[tid >> 6] = acc;
    __syncthreads();
    if (tid == 0) {
        const float s = (p4[0] + p4[1]) + (p4[2] + p4[3]);
        out[1 + n] = hidden[n] + tanhf(s + bi[n]);
    }
}

// ---------------- K5: y = sum(pred * h) ----------------
__global__ __launch_bounds__(256) void predk(
    const float* __restrict__ pred, const float* __restrict__ h,
    float* __restrict__ out)
{
    const int tid = threadIdx.x;
    float acc = 0.f;
    for (int i = tid; i < NN; i += 256) acc += pred[i] * h[i];
    acc = wred(acc);
    __shared__ float p4[4];
    if ((tid & 63) == 0) p4[tid >> 6] = acc;
    __syncthreads();
    if (tid == 0) out[0] = (p4[0] + p4[1]) + (p4[2] + p4[3]);
}

// ---------------- minimal fallback if ws too small ----------------
__global__ __launch_bounds__(256) void feat_kernel(
    const float* __restrict__ x, const float* __restrict__ hidden,
    const float* __restrict__ W1, const float* __restrict__ b1,
    const float* __restrict__ W2, const float* __restrict__ b2,
    float* __restrict__ feat)
{
    const int n = blockIdx.x, tid = threadIdx.x, lane = tid & 63, wave = tid >> 6;
    __shared__ float x_s[DD];
    __shared__ float f1_s[WW];
    *reinterpret_cast<float4*>(x_s + tid * 4) = *reinterpret_cast<const float4*>(x + tid * 4);
    if (tid == 0) feat[NROW + n] = hidden[n];
    __syncthreads();
    const float* W1n = W1 + (size_t)n * WW * DD;
    for (int r = wave * 32; r < wave * 32 + 32; ++r) {
        const float* row = W1n + (size_t)r * DD;
        float4 acc = {0.f, 0.f, 0.f, 0.f};
        #pragma unroll
        for (int it = 0; it < 4; ++it) {
            const float4 a  = *reinterpret_cast<const float4*>(row + it * 256 + lane * 4);
            const float4 xv = *reinterpret_cast<const float4*>(x_s + it * 256 + lane * 4);
            acc.x += a.x * xv.x; acc.y += a.y * xv.y;
            acc.z += a.z * xv.z; acc.w += a.w * xv.w;
        }
        float s = wred((acc.x + acc.y) + (acc.z + acc.w));
        if (lane == 0) {
            float v = s + b1[n * WW + r];
            f1_s[r] = v > 0.f ? v : 0.f;
        }
    }
    __syncthreads();
    const float* W2n = W2 + (size_t)n * WW * WW;
    for (int r = wave * 32; r < wave * 32 + 32; ++r) {
        const float2 a = *reinterpret_cast<const float2*>(W2n + (size_t)r * WW + lane * 2);
        const float2 f = *reinterpret_cast<const float2*>(f1_s + lane * 2);
        float s = wred(a.x * f.x + a.y * f.y);
        if (lane == 0) {
            float v = s + b2[n * WW + r];
            feat[n * WW + r] = v > 0.f ? v : 0.f;
        }
    }
}

__global__ __launch_bounds__(256) void sparse_kernel(
    const float* __restrict__ Wi, const float* __restrict__ mask,
    const float* __restrict__ bi, const float* __restrict__ hidden,
    const float* __restrict__ feat, float* __restrict__ out)
{
    const int n = blockIdx.x, tid = threadIdx.x;
    const float* mrow = mask + (size_t)n * FF;
    const float* wrow = Wi   + (size_t)n * FF;
    float acc = 0.f;
    for (int it = 0; it < FF / 1024; ++it) {
        const int f = it * 1024 + tid * 4;
        const float4 m = *reinterpret_cast<const float4*>(mrow + f);
        if (m.x != 0.f) acc += wrow[f + 0] * m.x * feat[f + 0];
        if (m.y != 0.f) acc += wrow[f + 1] * m.y * feat[f + 1];
        if (m.z != 0.f) acc += wrow[f + 2] * m.z * feat[f + 2];
        if (m.w != 0.f) acc += wrow[f + 3] * m.w * feat[f + 3];
    }
    acc = wred(acc);
    __shared__ float p4[4];
    if ((tid & 63) == 0) p4[tid >> 6] = acc;
    __syncthreads();
    if (tid == 0) {
        const float s = (p4[0] + p4[1]) + (p4[2] + p4[3]);
        out[1 + n] = hidden[n] + tanhf(s + bi[n]);
    }
}

extern "C" void kernel_launch(void* const* d_in, const int* in_sizes, int n_in,
                              void* d_out, int out_size, void* d_ws, size_t ws_size,
                              hipStream_t stream) {
    const float* x      = (const float*)d_in[0];
    const float* hidden = (const float*)d_in[1];
    const float* W1     = (const float*)d_in[2];
    const float* b1     = (const float*)d_in[3];
    const float* W2     = (const float*)d_in[4];
    const float* b2     = (const float*)d_in[5];
    const float* Wi     = (const float*)d_in[6];
    const float* bi     = (const float*)d_in[7];
    const float* mask   = (const float*)d_in[8];
    const float* pred   = (const float*)d_in[9];

    float* out     = (float*)d_out;
    float* feat    = (float*)d_ws;
    float* f1      = (float*)((char*)d_ws + WS_F1_OFF);
    float* partial = (float*)((char*)d_ws + WS_PART_OFF);

    if (ws_size >= WS_NEEDED) {
        w1dot<<<2048, 256, 0, stream>>>(x, W1, b1, f1);
        w2dot<<<2048, 256, 0, stream>>>(W2, b2, f1, hidden, feat);
        scangather<<<2048, 256, 0, stream>>>(mask, Wi, feat, partial);
        sumk<<<NN, 256, 0, stream>>>(partial, bi, hidden, out);
    } else {
        feat_kernel<<<NN, 256, 0, stream>>>(x, hidden, W1, b1, W2, b2, feat);
        sparse_kernel<<<NN, 256, 0, stream>>>(Wi, mask, bi, hidden, feat, out);
    }
    predk<<<1, 256, 0, stream>>>(pred, out + 1, out);
}